// Round 1
// baseline (647.314 us; speedup 1.0000x reference)
//
#include <hip/hip_runtime.h>
#include <stdint.h>

#define N_PTS 524288
#define DQ 64
#define HQ 256
#define WQ 256
#define MAP_BYTES (2*DQ*HQ*WQ*4)   /* 33554432 */

typedef short bf8  __attribute__((ext_vector_type(8)));
typedef float f16v __attribute__((ext_vector_type(16)));

static __device__ __forceinline__ short f2bf(float f) {
    union { float f; uint32_t u; } v; v.f = f;
    return (short)((v.u + 0x7fffu + ((v.u >> 16) & 1u)) >> 16);
}

__global__ void k_scatter(const int* __restrict__ coors, int* __restrict__ map) {
    int i = blockIdx.x * 256 + threadIdx.x;
    int4 c = ((const int4*)coors)[i];                 // b,z,y,x
    map[((c.x*DQ + c.y)*HQ + c.z)*WQ + c.w] = i;
}

__global__ void k_feats(const float* __restrict__ xf, const float* __restrict__ hf,
                        short* __restrict__ fb) {
    int t = blockIdx.x * 256 + threadIdx.x;           // t < N*8
    int n = t >> 3, seg = t & 7;
    const float* src = (seg < 4) ? (xf + n*32 + seg*8) : (hf + n*32 + seg*8 - 32);
    float4 a = ((const float4*)src)[0];
    float4 b = ((const float4*)src)[1];
    bf8 r;
    r[0]=f2bf(a.x); r[1]=f2bf(a.y); r[2]=f2bf(a.z); r[3]=f2bf(a.w);
    r[4]=f2bf(b.x); r[5]=f2bf(b.y); r[6]=f2bf(b.z); r[7]=f2bf(b.w);
    ((bf8*)fb)[t] = r;
}

__global__ void k_wt(const float* __restrict__ w, short* __restrict__ wt) {
    int t = blockIdx.x * 256 + threadIdx.x;
    if (t >= 27*64*128) return;
    int jj = t & 7, c = (t >> 3) & 127, jg = (t >> 10) & 7, k = t >> 13;
    int j = jg*8 + jj;
    wt[t] = f2bf(w[(k*64 + j)*128 + c]);              // Wt[k][jg][c][jj] = W[k][j][c]
}

__launch_bounds__(256, 2)
__global__ void k_main(const int* __restrict__ map, const short* __restrict__ fb,
                       const short* __restrict__ wt, const float* __restrict__ bias,
                       const float* __restrict__ cfeat, const int* __restrict__ coors,
                       float* __restrict__ out)
{
    __shared__ short Alds[8*256*8];   // [jg][m 0..255][jj]  32 kB
    __shared__ short Wlds[8*128*8];   // [jg][c 0..127][jj]  16 kB

    const int tid  = threadIdx.x;
    const int lane = tid & 63;
    const int wv   = tid >> 6;
    const int l31  = lane & 31;
    const int lhi  = lane >> 5;

    const int pbase = blockIdx.x * 256;
    const int prow  = wv*64 + lane;       // this lane's gather row (block-local)
    const int p     = pbase + prow;

    const int4 cr = ((const int4*)coors)[p];   // b,z,y,x

    f16v acc[2][4];
    #pragma unroll
    for (int mt = 0; mt < 2; mt++)
        #pragma unroll
        for (int ct = 0; ct < 4; ct++) {
            float bv = bias[ct*32 + l31];
            #pragma unroll
            for (int r = 0; r < 16; r++) acc[mt][ct][r] = bv;
        }

    for (int ko = 0; ko < 27; ko++) {
        __syncthreads();   // previous k's MFMA reads done before overwriting LDS

        // ---- stage W[ko] slice (16 kB) ----
        {
            const int4* wsrc = (const int4*)(wt + ko*8192);
            int4* wdst = (int4*)Wlds;
            #pragma unroll
            for (int i = 0; i < 4; i++) wdst[i*256 + tid] = wsrc[i*256 + tid];
        }

        // ---- probe map + gather this lane's row into Alds ----
        {
            int dz = ko/9 - 1, dy = (ko/3)%3 - 1, dxo = ko%3 - 1;
            int nz = cr.y + dz, ny = cr.z + dy, nx = cr.w + dxo;
            int nid = -1;
            if ((unsigned)nz < (unsigned)DQ && (unsigned)ny < (unsigned)HQ &&
                (unsigned)nx < (unsigned)WQ)
                nid = map[((cr.x*DQ + nz)*HQ + ny)*WQ + nx];
            int4 ch[8];
            if (nid >= 0) {
                const int4* src = (const int4*)(fb + nid*64);   // 128 B bf16 row
                #pragma unroll
                for (int g = 0; g < 8; g++) ch[g] = src[g];
            } else {
                #pragma unroll
                for (int g = 0; g < 8; g++) ch[g] = make_int4(0,0,0,0);
            }
            int4* ad = (int4*)Alds;
            #pragma unroll
            for (int g = 0; g < 8; g++) ad[g*256 + prow] = ch[g];
        }

        __syncthreads();

        // ---- MFMA: wave owns rows [wv*64, wv*64+64), all 128 cols ----
        #pragma unroll
        for (int ks = 0; ks < 4; ks++) {
            int jg = ks*2 + lhi;
            bf8 a0 = *(const bf8*)&Alds[(jg*256 + wv*64 +      l31)*8];
            bf8 a1 = *(const bf8*)&Alds[(jg*256 + wv*64 + 32 + l31)*8];
            #pragma unroll
            for (int ct = 0; ct < 4; ct++) {
                bf8 b = *(const bf8*)&Wlds[(jg*128 + ct*32 + l31)*8];
                acc[0][ct] = __builtin_amdgcn_mfma_f32_32x32x16_bf16(a0, b, acc[0][ct], 0, 0, 0);
                acc[1][ct] = __builtin_amdgcn_mfma_f32_32x32x16_bf16(a1, b, acc[1][ct], 0, 0, 0);
            }
        }
    }

    // ---- epilogue: LSTM gates, lane-local ----
    #pragma unroll
    for (int mt = 0; mt < 2; mt++) {
        #pragma unroll
        for (int r = 0; r < 16; r++) {
            int row = (r & 3) + 8*(r >> 2) + 4*lhi;
            int pp  = pbase + wv*64 + mt*32 + row;
            float gi = acc[mt][0][r];
            float gf = acc[mt][1][r];
            float go = acc[mt][2][r];
            float gg = acc[mt][3][r];
            float cv = cfeat[pp*32 + l31];
            float si = 1.f / (1.f + __expf(-gi));
            float sf = 1.f / (1.f + __expf(-gf));
            float so = 1.f / (1.f + __expf(-go));
            float tg = tanhf(gg);
            float cn = sf*cv + si*tg;
            float hn = so * tanhf(cn);
            out[pp*32 + l31] = hn;
            out[N_PTS*32 + pp*32 + l31] = cn;
        }
    }
}

extern "C" void kernel_launch(void* const* d_in, const int* in_sizes, int n_in,
                              void* d_out, int out_size, void* d_ws, size_t ws_size,
                              hipStream_t stream) {
    const float* xf    = (const float*)d_in[0];
    const float* hf    = (const float*)d_in[1];
    const float* cf    = (const float*)d_in[2];
    const float* w     = (const float*)d_in[3];
    const float* bias  = (const float*)d_in[4];
    const int*   coors = (const int*)d_in[5];
    float* out = (float*)d_out;

    int*   map = (int*)d_ws;
    short* fb  = (short*)((char*)d_ws + MAP_BYTES);
    short* wtb = (short*)((char*)d_ws + MAP_BYTES + (size_t)N_PTS*64*2);

    hipMemsetAsync(map, 0xFF, MAP_BYTES, stream);                       // map = -1
    k_scatter<<<N_PTS/256, 256, 0, stream>>>(coors, map);
    k_feats<<<(N_PTS*8)/256, 256, 0, stream>>>(xf, hf, fb);
    k_wt<<<(27*64*128 + 255)/256, 256, 0, stream>>>(w, wtb);
    k_main<<<N_PTS/256, 256, 0, stream>>>(map, fb, wtb, bias, cf, coors, out);
}